// Round 4
// baseline (140.148 us; speedup 1.0000x reference)
//
#include <hip/hip_runtime.h>
#include <math.h>

#define EPS_BN 1e-5f

typedef __attribute__((ext_vector_type(8))) short short8;
typedef __attribute__((ext_vector_type(4))) float f32x4;

__device__ __forceinline__ unsigned short f2bf(float f) {
    unsigned int u = __float_as_uint(f);
    u = (u + 0x7fffu + ((u >> 16) & 1u)) >> 16;
    return (unsigned short)u;
}
__device__ __forceinline__ float bf2f(unsigned short s) {
    return __uint_as_float(((unsigned int)s) << 16);
}
__device__ __forceinline__ float elu1(float y) { return y > 0.f ? y : expm1f(y); }
__device__ __forceinline__ float warp_sum(float v) {
    for (int off = 32; off > 0; off >>= 1) v += __shfl_down(v, off);
    return v;
}

// ---------------- workspace layout (ushort indices) ----------------
#define UW1 0        // [10][32][64]   20480
#define UW2 20480    // [10][64][32]   20480
#define UW3 40960    // [10][128][64]  81920
#define UW4 122880   // [10][224][128] 286720 -> end 409600 ush = 819200 B
#define BB1 0
#define BB2 32
#define BB3 96
#define BB4 224

// ---------------- LDS layout (byte offsets) ----------------
// xT region: stage1 x-tile 592*72*2 = 85248; later z2 (108*72*2=15552) @0,
//            z4 f32 (1400*4=5600) @16384.
// z1 region: 396*40*2 = 31680 @85248; later z3 (44*136*2=11968) @85248,
//            head scratch (feats 16B + h1s 2048B) @85248+12288.
// zb pool scratch: 4 waves * 48*32*2 = 12288 @116928.  total = 129216 B.
#define L_XT   0
#define L_Z2   0
#define L_Z4   16384
#define L_Z1   85248
#define L_Z3   85248
#define L_HEAD (85248 + 12288)
#define L_ZB   116928
#define XROWS  592

// ---------------------------------------------------------------------------
// prep: BN-folded, zero-padded bf16 weights + fused biases (same as round 3).
// ---------------------------------------------------------------------------
__global__ __launch_bounds__(256) void kprep(
    const float* __restrict__ w_time, const float* __restrict__ b_time,
    const float* __restrict__ w_spat,
    const float* __restrict__ w2, const float* __restrict__ w3,
    const float* __restrict__ w4,
    const float* __restrict__ g1, const float* __restrict__ be1,
    const float* __restrict__ m1, const float* __restrict__ v1,
    const float* __restrict__ g2, const float* __restrict__ be2,
    const float* __restrict__ m2, const float* __restrict__ v2,
    const float* __restrict__ g3, const float* __restrict__ be3,
    const float* __restrict__ m3, const float* __restrict__ v3,
    const float* __restrict__ g4, const float* __restrict__ be4,
    const float* __restrict__ m4, const float* __restrict__ v4,
    unsigned short* __restrict__ wsu, float* __restrict__ biasf) {
    int idx = blockIdx.x * 256 + threadIdx.x;
    if (idx < 20480) {                       // Wpk1 [10][32][64]
        int k = idx >> 11, g = (idx >> 6) & 31, c = idx & 63;
        float val = 0.f;
        if (g < 25) {
            float s = 0.f;
#pragma unroll
            for (int f = 0; f < 25; ++f)
                s = fmaf(w_spat[g * 1600 + f * 64 + c], w_time[f * 10 + k], s);
            val = s * (g1[g] * rsqrtf(v1[g] + EPS_BN));
        }
        wsu[UW1 + idx] = f2bf(val);
    } else if (idx < 40960) {                // Wpk2 [10][64][32]
        int j = idx - 20480;
        int k = j >> 11, g = (j >> 5) & 63, c = j & 31;
        float val = 0.f;
        if (g < 50 && c < 25)
            val = w2[(g * 25 + c) * 10 + k] * (g2[g] * rsqrtf(v2[g] + EPS_BN));
        wsu[UW2 + j] = f2bf(val);
    } else if (idx < 122880) {               // Wpk3 [10][128][64]
        int j = idx - 40960;
        int k = j >> 13, g = (j >> 6) & 127, c = j & 63;
        float val = 0.f;
        if (g < 100 && c < 50)
            val = w3[(g * 50 + c) * 10 + k] * (g3[g] * rsqrtf(v3[g] + EPS_BN));
        wsu[UW3 + j] = f2bf(val);
    } else if (idx < 409600) {               // Wpk4 [10][224][128]
        int j = idx - 122880;
        int k = j / 28672, r = j % 28672, g = r >> 7, c = r & 127;
        float val = 0.f;
        if (g < 200 && c < 100)
            val = w4[(g * 100 + c) * 10 + k] * (g4[g] * rsqrtf(v4[g] + EPS_BN));
        wsu[UW4 + j] = f2bf(val);
    } else if (idx < 410048) {               // biases
        int j = idx - 409600;
        if (j < 32) {
            int g = j; float val = 0.f;
            if (g < 25) {
                float beff = 0.f;
                for (int f = 0; f < 25; ++f) {
                    float a = 0.f;
                    for (int c = 0; c < 64; ++c) a += w_spat[g * 1600 + f * 64 + c];
                    beff = fmaf(a, b_time[f], beff);
                }
                float sc = g1[g] * rsqrtf(v1[g] + EPS_BN);
                val = be1[g] - m1[g] * sc + beff * sc;
            }
            biasf[BB1 + g] = val;
        } else if (j < 96) {
            int g = j - 32; float val = 0.f;
            if (g < 50) { float sc = g2[g] * rsqrtf(v2[g] + EPS_BN); val = be2[g] - m2[g] * sc; }
            biasf[BB2 + g] = val;
        } else if (j < 224) {
            int g = j - 96; float val = 0.f;
            if (g < 100) { float sc = g3[g] * rsqrtf(v3[g] + EPS_BN); val = be3[g] - m3[g] * sc; }
            biasf[BB3 + g] = val;
        } else {
            int g = j - 224; float val = 0.f;
            if (g < 200) { float sc = g4[g] * rsqrtf(v4[g] + EPS_BN); val = be4[g] - m4[g] * sc; }
            biasf[BB4 + g] = val;
        }
    }
}

// ---------------------------------------------------------------------------
// conv_core: one MFMA conv(K=10)+bias+ELU+pool3 stage, LDS in -> LDS out.
// A rows = conv-time, A cols = cin (CPAD). B = Wpk[k][g][c] (global/L2).
// Per wave-job: 32 output channels (2 gh halves of 16) x TT*16 conv rows
// -> NCHUNK*16 pooled rows, bounced via per-wave zb for the pool transpose.
// ---------------------------------------------------------------------------
template<int CPAD, int RS, int SP, int TT, int TPC, int NCHUNK, int JMAX,
         int NTCH, int GPAD, int TPOOL, int GSTORE, int NGV, int OUT_RS,
         bool OUT_F32>
__device__ __forceinline__ void conv_core(
    const unsigned short* xT, const unsigned short* __restrict__ wpk,
    const float* __restrict__ bias,
    unsigned short* zout, float* zoutf, unsigned short* zb,
    int t, int jbeg, int jend, int t0b) {
    const int lane = t & 63;
    const int wv = __builtin_amdgcn_readfirstlane(t >> 6);
    const int lm = lane & 15, h8 = lane >> 4;
    const int gloc = lane & 31, hh = lane >> 5;
    unsigned short* zbw = zb + wv * (48 * 32);

    for (int job = jbeg + wv; job < jend; job += 4) {
        const int gbi = job / NTCH, tci = job % NTCH;
        const int tl0 = tci * (TT * 16) - t0b;
        const int po0 = tci * (NCHUNK * 16);

        f32x4 acc[TT][2];
#pragma unroll
        for (int i = 0; i < TT; ++i) {
            acc[i][0] = (f32x4){0.f, 0.f, 0.f, 0.f};
            acc[i][1] = (f32x4){0.f, 0.f, 0.f, 0.f};
        }

        const int abase = (tl0 + lm) * RS + h8 * 8;
        const unsigned short* wp = wpk + (gbi * 32 + lm) * CPAD + h8 * 8;
#pragma unroll
        for (int k = 0; k < 10; ++k) {
            short8 w0[SP], w1[SP];
#pragma unroll
            for (int s = 0; s < SP; ++s) {
                w0[s] = *(const short8*)(wp + k * (GPAD * CPAD) + s * 32);
                w1[s] = *(const short8*)(wp + k * (GPAD * CPAD) + 16 * CPAD + s * 32);
            }
#pragma unroll
            for (int s = 0; s < SP; ++s) {
#pragma unroll
                for (int tt = 0; tt < TT; ++tt) {
                    short8 a = *(const short8*)&xT[abase + (tt * 16 + k) * RS + s * 32];
                    acc[tt][0] = __builtin_amdgcn_mfma_f32_16x16x32_bf16(
                        a, w0[s], acc[tt][0], 0, 0, 0);
                    acc[tt][1] = __builtin_amdgcn_mfma_f32_16x16x32_bf16(
                        a, w1[s], acc[tt][1], 0, 0, 0);
                }
            }
        }

        const float bv0 = bias[gbi * 32 + lm];
        const float bv1 = bias[gbi * 32 + 16 + lm];
#pragma unroll
        for (int ch = 0; ch < NCHUNK; ++ch) {
#pragma unroll
            for (int ti = 0; ti < TPC; ++ti) {
                int ttg = ch * TPC + ti;
#pragma unroll
                for (int r = 0; r < 4; ++r) {
                    float v0 = elu1(acc[ttg][0][r] + bv0);
                    float v1 = elu1(acc[ttg][1][r] + bv1);
                    int row = ti * 16 + 4 * h8 + r;
                    zbw[row * 32 + lm] = f2bf(v0);
                    zbw[row * 32 + 16 + lm] = f2bf(v1);
                }
            }
#pragma unroll
            for (int j = 0; j < JMAX; ++j) {
                int po = hh + 2 * j;
                if (3 * po + 2 < TPC * 16) {
                    float q0 = bf2f(zbw[(3 * po) * 32 + gloc]);
                    float q1 = bf2f(zbw[(3 * po + 1) * 32 + gloc]);
                    float q2 = bf2f(zbw[(3 * po + 2) * 32 + gloc]);
                    float mx = fmaxf(q0, fmaxf(q1, q2));
                    int poa = po0 + ch * 16 + po;
                    int ga = gbi * 32 + gloc;
                    if (poa < TPOOL && ga < GSTORE) {
                        if constexpr (OUT_F32)
                            zoutf[poa * OUT_RS + ga] = mx;
                        else
                            zout[poa * OUT_RS + ga] =
                                (ga < NGV) ? f2bf(mx) : (unsigned short)0;
                    }
                }
            }
        }
    }
}

// ---------------------------------------------------------------------------
// megakernel: one block per sample; whole pipeline in LDS.
// ---------------------------------------------------------------------------
__global__ __launch_bounds__(256) void kmega(
    const float* __restrict__ x, const unsigned short* __restrict__ wsu,
    const float* __restrict__ biasf,
    const float* __restrict__ w_cls, const float* __restrict__ b_cls,
    const int* __restrict__ cid,
    const float* __restrict__ hW1, const float* __restrict__ hb1,
    const float* __restrict__ hW2, const float* __restrict__ hb2,
    const float* __restrict__ hg, const float* __restrict__ hbe,
    const float* __restrict__ hm, const float* __restrict__ hv,
    float* __restrict__ out) {
    __shared__ __align__(16) unsigned char smem[129216];
    unsigned short* xT  = (unsigned short*)(smem + L_XT);
    unsigned short* z1u = (unsigned short*)(smem + L_Z1);
    unsigned short* z2u = (unsigned short*)(smem + L_Z2);
    unsigned short* z3u = (unsigned short*)(smem + L_Z3);
    float*          z4f = (float*)(smem + L_Z4);
    unsigned short* zb  = (unsigned short*)(smem + L_ZB);
    float*          feats = (float*)(smem + L_HEAD);
    float*          h1s   = (float*)(smem + L_HEAD + 16);

    const int b = blockIdx.x, t = threadIdx.x;
    const float* xb = x + b * 64000;

    // ================= stage 1 (two x passes) =================
#pragma unroll 1
    for (int pass = 0; pass < 2; ++pass) {
        const int t0 = pass * 576;
        // stage x tile: bf16 transposed [t][c], rows t0..t0+592
        for (int idx = t; idx < 32 * (XROWS / 4); idx += 256) {
            int cp = idx / (XROWS / 4), t4 = idx - cp * (XROWS / 4);
            int r0 = 4 * t4, tg = t0 + r0;
            float4 va = {0, 0, 0, 0}, vb = {0, 0, 0, 0};
            if (tg < 1000) {
                va = *(const float4*)(xb + (2 * cp) * 1000 + tg);
                vb = *(const float4*)(xb + (2 * cp + 1) * 1000 + tg);
            }
            const float* pa = (const float*)&va;
            const float* pb = (const float*)&vb;
#pragma unroll
            for (int i2 = 0; i2 < 4; ++i2) {
                unsigned int pk = (unsigned int)f2bf(pa[i2]) |
                                  ((unsigned int)f2bf(pb[i2]) << 16);
                *(unsigned int*)&xT[(r0 + i2) * 72 + 2 * cp] = pk;
            }
        }
        if (pass == 1) {   // zero z1 tail rows 330..396 (read by stage2 chunk 3)
            for (int i = t; i < 1320; i += 256)
                *(unsigned int*)&z1u[330 * 40 + 2 * i] = 0u;
        }
        __syncthreads();
        // compute chunks of this pass
        conv_core<64, 72, 2, 6, 3, 2, 8, 16, 32, 330, 32, 25, 40, false>(
            xT, wsu + UW1, biasf + BB1, z1u, nullptr, zb, t,
            pass == 0 ? 0 : 6, pass == 0 ? 6 : 11, t0);
        __syncthreads();
    }

    // ================= stage 2: z1 -> z2 =================
    conv_core<32, 40, 1, 6, 3, 2, 8, 4, 64, 107, 64, 50, 72, false>(
        z1u, wsu + UW2, biasf + BB2, z2u, nullptr, zb, t, 0, 8, 0);
    __syncthreads();

    // ================= stage 3: z2 -> z3 =================
    for (int i = t; i < 816; i += 256)    // zero z3 tail rows 32..44
        *(unsigned int*)&z3u[32 * 136 + 2 * i] = 0u;
    conv_core<64, 72, 2, 6, 3, 2, 8, 1, 128, 32, 128, 100, 136, false>(
        z2u, wsu + UW3, biasf + BB3, z3u, nullptr, zb, t, 0, 4, 0);
    __syncthreads();

    // ================= stage 4: z3 -> z4 (f32) =================
    conv_core<128, 136, 4, 2, 2, 1, 4, 1, 224, 7, 200, 200, 200, true>(
        z3u, wsu + UW4, biasf + BB4, nullptr, z4f, zb, t, 0, 7, 0);
    __syncthreads();

    // ================= head =================
    const int wv = t >> 6, lane = t & 63;
    {
        float p = 0.f;
        for (int i = lane; i < 1400; i += 64) {
            int po = i / 200, g = i - po * 200;
            p = fmaf(z4f[i], w_cls[wv * 1400 + g * 7 + po], p);
        }
        p = warp_sum(p);
        if (lane == 0) feats[wv] = p + b_cls[wv];
    }
    __syncthreads();

    const int c = cid[b];
    const float f0 = feats[0], f1 = feats[1], f2 = feats[2], f3 = feats[3];
    for (int h = t; h < 512; h += 256) {
        const float* w1 = &hW1[(c * 512 + h) * 4];
        float v = f0 * w1[0] + f1 * w1[1] + f2 * w1[2] + f3 * w1[3] + hb1[c * 512 + h];
        float sc = hg[c * 512 + h] * rsqrtf(hv[c * 512 + h] + EPS_BN);
        v = (v - hm[c * 512 + h]) * sc + hbe[c * 512 + h];
        h1s[h] = fmaxf(v, 0.f);
    }
    __syncthreads();
    {
        float p = 0.f;
        for (int i = lane; i < 512; i += 64)
            p = fmaf(h1s[i], hW2[(c * 4 + wv) * 512 + i], p);
        p = warp_sum(p);
        if (lane == 0) out[b * 4 + wv] = p + hb2[c * 4 + wv];
    }
}

// ---------------------------------------------------------------------------
extern "C" void kernel_launch(void* const* d_in, const int* in_sizes, int n_in,
                              void* d_out, int out_size, void* d_ws, size_t ws_size,
                              hipStream_t stream) {
    const float* x      = (const float*)d_in[0];
    const int*   cid    = (const int*)d_in[1];
    const float* w_time = (const float*)d_in[2];
    const float* b_time = (const float*)d_in[3];
    const float* w_spat = (const float*)d_in[4];
    const float* w2     = (const float*)d_in[5];
    const float* w3     = (const float*)d_in[6];
    const float* w4     = (const float*)d_in[7];
    const float* w_cls  = (const float*)d_in[8];
    const float* b_cls  = (const float*)d_in[9];
    const float* hW1    = (const float*)d_in[10];
    const float* hb1    = (const float*)d_in[11];
    const float* hW2    = (const float*)d_in[12];
    const float* hb2    = (const float*)d_in[13];
    const float* hg     = (const float*)d_in[14];
    const float* hbe    = (const float*)d_in[15];
    const float* hm     = (const float*)d_in[16];
    const float* hv     = (const float*)d_in[17];
    const float* g1  = (const float*)d_in[18];
    const float* be1 = (const float*)d_in[19];
    const float* m1  = (const float*)d_in[20];
    const float* v1  = (const float*)d_in[21];
    const float* g2  = (const float*)d_in[22];
    const float* be2 = (const float*)d_in[23];
    const float* m2  = (const float*)d_in[24];
    const float* v2  = (const float*)d_in[25];
    const float* g3  = (const float*)d_in[26];
    const float* be3 = (const float*)d_in[27];
    const float* m3  = (const float*)d_in[28];
    const float* v3  = (const float*)d_in[29];
    const float* g4  = (const float*)d_in[30];
    const float* be4 = (const float*)d_in[31];
    const float* m4  = (const float*)d_in[32];
    const float* v4  = (const float*)d_in[33];

    unsigned short* wsu = (unsigned short*)d_ws;
    float* biasf = (float*)((char*)d_ws + 819200);
    float* out = (float*)d_out;

    kprep<<<1602, 256, 0, stream>>>(w_time, b_time, w_spat, w2, w3, w4,
                                    g1, be1, m1, v1, g2, be2, m2, v2,
                                    g3, be3, m3, v3, g4, be4, m4, v4,
                                    wsu, biasf);

    kmega<<<128, 256, 0, stream>>>(x, wsu, biasf, w_cls, b_cls, cid,
                                   hW1, hb1, hW2, hb2, hg, hbe, hm, hv, out);
}

// Round 5
// 108.041 us; speedup vs baseline: 1.2972x; 1.2972x over previous
//
#include <hip/hip_runtime.h>
#include <math.h>

#define EPS_BN 1e-5f

typedef __attribute__((ext_vector_type(8))) short short8;
typedef __attribute__((ext_vector_type(4))) float f32x4;
typedef __attribute__((ext_vector_type(4))) unsigned int uint4v;

__device__ __forceinline__ unsigned short f2bf(float f) {
    unsigned int u = __float_as_uint(f);
    u = (u + 0x7fffu + ((u >> 16) & 1u)) >> 16;
    return (unsigned short)u;
}
__device__ __forceinline__ float bf2f(unsigned short s) {
    return __uint_as_float(((unsigned int)s) << 16);
}
__device__ __forceinline__ float elu1(float y) { return y > 0.f ? y : expm1f(y); }
__device__ __forceinline__ float warp_sum(float v) {
    for (int off = 32; off > 0; off >>= 1) v += __shfl_down(v, off);
    return v;
}

// ---------------- workspace layout ----------------
// ushort units from d_ws: weights
#define UW1 0        // [10][32][64]   20480
#define UW2 20480    // [10][64][32]   20480
#define UW3 40960    // [10][128][64]  81920
#define UW4 122880   // [10][224][128] 286720 -> ends 409600 ush (819200 B)
// float units within biasf (byte 819200): 448 floats -> ends byte 820992
#define BB1 0
#define BB2 32
#define BB3 96
#define BB4 224
// activations (ushort units from d_ws):
#define XTG_U 410496    // xT  [128][1072][64]  (byte 820992)
#define Z1G_U 9192320   // z1  [128][330][32]   (byte 18384640)
#define Z2G_U 10544000  // z2  [128][107][64]   (byte 21088000)

#define NPREP 1602
#define RS_ZB 36

// ---------------------------------------------------------------------------
// kprep_tr: blocks [0,NPREP) = BN-folded bf16 weight prep (verified round 3);
//           blocks >= NPREP  = tiled x transpose -> xT bf16 [b][t][c].
// ---------------------------------------------------------------------------
__global__ __launch_bounds__(256) void kprep_tr(
    const float* __restrict__ x,
    const float* __restrict__ w_time, const float* __restrict__ b_time,
    const float* __restrict__ w_spat,
    const float* __restrict__ w2, const float* __restrict__ w3,
    const float* __restrict__ w4,
    const float* __restrict__ g1, const float* __restrict__ be1,
    const float* __restrict__ m1, const float* __restrict__ v1,
    const float* __restrict__ g2, const float* __restrict__ be2,
    const float* __restrict__ m2, const float* __restrict__ v2,
    const float* __restrict__ g3, const float* __restrict__ be3,
    const float* __restrict__ m3, const float* __restrict__ v3,
    const float* __restrict__ g4, const float* __restrict__ be4,
    const float* __restrict__ m4, const float* __restrict__ v4,
    unsigned short* __restrict__ wsz, float* __restrict__ biasf) {
    __shared__ float tr[64 * 65];
    if (blockIdx.x < NPREP) {
        int idx = blockIdx.x * 256 + threadIdx.x;
        if (idx < 20480) {                       // Wpk1 [10][32][64]
            int k = idx >> 11, g = (idx >> 6) & 31, c = idx & 63;
            float val = 0.f;
            if (g < 25) {
                float s = 0.f;
#pragma unroll
                for (int f = 0; f < 25; ++f)
                    s = fmaf(w_spat[g * 1600 + f * 64 + c], w_time[f * 10 + k], s);
                val = s * (g1[g] * rsqrtf(v1[g] + EPS_BN));
            }
            wsz[UW1 + idx] = f2bf(val);
        } else if (idx < 40960) {                // Wpk2 [10][64][32]
            int j = idx - 20480;
            int k = j >> 11, g = (j >> 5) & 63, c = j & 31;
            float val = 0.f;
            if (g < 50 && c < 25)
                val = w2[(g * 25 + c) * 10 + k] * (g2[g] * rsqrtf(v2[g] + EPS_BN));
            wsz[UW2 + j] = f2bf(val);
        } else if (idx < 122880) {               // Wpk3 [10][128][64]
            int j = idx - 40960;
            int k = j >> 13, g = (j >> 6) & 127, c = j & 63;
            float val = 0.f;
            if (g < 100 && c < 50)
                val = w3[(g * 50 + c) * 10 + k] * (g3[g] * rsqrtf(v3[g] + EPS_BN));
            wsz[UW3 + j] = f2bf(val);
        } else if (idx < 409600) {               // Wpk4 [10][224][128]
            int j = idx - 122880;
            int k = j / 28672, r = j % 28672, g = r >> 7, c = r & 127;
            float val = 0.f;
            if (g < 200 && c < 100)
                val = w4[(g * 100 + c) * 10 + k] * (g4[g] * rsqrtf(v4[g] + EPS_BN));
            wsz[UW4 + j] = f2bf(val);
        } else if (idx < 410048) {               // biases
            int j = idx - 409600;
            if (j < 32) {
                int g = j; float val = 0.f;
                if (g < 25) {
                    float beff = 0.f;
                    for (int f = 0; f < 25; ++f) {
                        float a = 0.f;
                        for (int c = 0; c < 64; ++c) a += w_spat[g * 1600 + f * 64 + c];
                        beff = fmaf(a, b_time[f], beff);
                    }
                    float sc = g1[g] * rsqrtf(v1[g] + EPS_BN);
                    val = be1[g] - m1[g] * sc + beff * sc;
                }
                biasf[BB1 + g] = val;
            } else if (j < 96) {
                int g = j - 32; float val = 0.f;
                if (g < 50) { float sc = g2[g] * rsqrtf(v2[g] + EPS_BN); val = be2[g] - m2[g] * sc; }
                biasf[BB2 + g] = val;
            } else if (j < 224) {
                int g = j - 96; float val = 0.f;
                if (g < 100) { float sc = g3[g] * rsqrtf(v3[g] + EPS_BN); val = be3[g] - m3[g] * sc; }
                biasf[BB3 + g] = val;
            } else {
                int g = j - 224; float val = 0.f;
                if (g < 200) { float sc = g4[g] * rsqrtf(v4[g] + EPS_BN); val = be4[g] - m4[g] * sc; }
                biasf[BB4 + g] = val;
            }
        }
    } else {
        // ------- x transpose: tile (b, 64 t) -> xT[b][t][c] bf16 -------
        const int bid = blockIdx.x - NPREP;
        const int b = bid / 17, tile = bid % 17, t = threadIdx.x;
        const int t0 = tile * 64;
        const float* xb = x + b * 64000;
        for (int idx = t; idx < 1024; idx += 256) {
            int c = idx >> 4, q = idx & 15;
            int tg = t0 + 4 * q;
            float4 v = {0.f, 0.f, 0.f, 0.f};
            if (tg + 4 <= 1000) {
                v = *(const float4*)(xb + c * 1000 + tg);
            } else {
                float* pv = (float*)&v;
#pragma unroll
                for (int e = 0; e < 4; ++e)
                    if (tg + e < 1000) pv[e] = xb[c * 1000 + tg + e];
            }
            tr[c * 65 + 4 * q]     = v.x;
            tr[c * 65 + 4 * q + 1] = v.y;
            tr[c * 65 + 4 * q + 2] = v.z;
            tr[c * 65 + 4 * q + 3] = v.w;
        }
        __syncthreads();
        unsigned short* xTg = wsz + XTG_U;
        for (int idx = t; idx < 2048; idx += 256) {
            int tl = idx >> 5, cp = idx & 31;
            int tg = t0 + tl;
            unsigned int pk = 0u;
            if (tg < 1000)
                pk = (unsigned int)f2bf(tr[(2 * cp) * 65 + tl]) |
                     ((unsigned int)f2bf(tr[(2 * cp + 1) * 65 + tl]) << 16);
            if (tg < 1072)
                *(unsigned int*)&xTg[(b * 1072 + tg) * 64 + 2 * cp] = pk;
        }
    }
}

// ---------------------------------------------------------------------------
// conv_core: MFMA conv(K=10)+bias+ELU+pool3, LDS A-tile -> out (LDS or global).
// Identical math to the round-3/4 verified core; zb stride = 36 (conflict fix).
// ---------------------------------------------------------------------------
template<int CPAD, int RS, int SP, int TT, int TPC, int NCHUNK, int JMAX,
         int NTCH, int GPAD, int TPOOL, int GSTORE, int NGV, int OUT_RS,
         bool OUT_F32, int NW>
__device__ __forceinline__ void conv_core(
    const unsigned short* xT, const unsigned short* __restrict__ wpk,
    const float* __restrict__ bias,
    unsigned short* zout, float* zoutf, unsigned short* zb,
    int t, int jbeg, int jend, int t0b) {
    const int lane = t & 63;
    const int wv = __builtin_amdgcn_readfirstlane(t >> 6);
    const int lm = lane & 15, h8 = lane >> 4;
    const int gloc = lane & 31, hh = lane >> 5;
    unsigned short* zbw = zb + wv * (48 * RS_ZB);

    for (int job = jbeg + wv; job < jend; job += NW) {
        const int gbi = job / NTCH, tci = job % NTCH;
        const int tl0 = tci * (TT * 16) - t0b;
        const int po0 = tci * (NCHUNK * 16);

        f32x4 acc[TT][2];
#pragma unroll
        for (int i = 0; i < TT; ++i) {
            acc[i][0] = (f32x4){0.f, 0.f, 0.f, 0.f};
            acc[i][1] = (f32x4){0.f, 0.f, 0.f, 0.f};
        }

        const int abase = (tl0 + lm) * RS + h8 * 8;
        const unsigned short* wp = wpk + (gbi * 32 + lm) * CPAD + h8 * 8;
#pragma unroll
        for (int k = 0; k < 10; ++k) {
            short8 w0[SP], w1[SP];
#pragma unroll
            for (int s = 0; s < SP; ++s) {
                w0[s] = *(const short8*)(wp + k * (GPAD * CPAD) + s * 32);
                w1[s] = *(const short8*)(wp + k * (GPAD * CPAD) + 16 * CPAD + s * 32);
            }
#pragma unroll
            for (int s = 0; s < SP; ++s) {
#pragma unroll
                for (int tt = 0; tt < TT; ++tt) {
                    short8 a = *(const short8*)&xT[abase + (tt * 16 + k) * RS + s * 32];
                    acc[tt][0] = __builtin_amdgcn_mfma_f32_16x16x32_bf16(
                        a, w0[s], acc[tt][0], 0, 0, 0);
                    acc[tt][1] = __builtin_amdgcn_mfma_f32_16x16x32_bf16(
                        a, w1[s], acc[tt][1], 0, 0, 0);
                }
            }
        }

        const float bv0 = bias[gbi * 32 + lm];
        const float bv1 = bias[gbi * 32 + 16 + lm];
#pragma unroll
        for (int ch = 0; ch < NCHUNK; ++ch) {
#pragma unroll
            for (int ti = 0; ti < TPC; ++ti) {
                int ttg = ch * TPC + ti;
#pragma unroll
                for (int r = 0; r < 4; ++r) {
                    float v0 = elu1(acc[ttg][0][r] + bv0);
                    float v1 = elu1(acc[ttg][1][r] + bv1);
                    int row = ti * 16 + 4 * h8 + r;
                    zbw[row * RS_ZB + lm] = f2bf(v0);
                    zbw[row * RS_ZB + 16 + lm] = f2bf(v1);
                }
            }
#pragma unroll
            for (int j = 0; j < JMAX; ++j) {
                int po = hh + 2 * j;
                if (3 * po + 2 < TPC * 16) {
                    float q0 = bf2f(zbw[(3 * po) * RS_ZB + gloc]);
                    float q1 = bf2f(zbw[(3 * po + 1) * RS_ZB + gloc]);
                    float q2 = bf2f(zbw[(3 * po + 2) * RS_ZB + gloc]);
                    float mx = fmaxf(q0, fmaxf(q1, q2));
                    int poa = po0 + ch * 16 + po;
                    int ga = gbi * 32 + gloc;
                    if (poa < TPOOL && ga < GSTORE) {
                        if constexpr (OUT_F32)
                            zoutf[poa * OUT_RS + ga] = mx;
                        else
                            zout[poa * OUT_RS + ga] =
                                (ga < NGV) ? f2bf(mx) : (unsigned short)0;
                    }
                }
            }
        }
    }
}

// ---------------------------------------------------------------------------
// ks1: stage1. grid (128, 11), 64 threads = 1 wave = 1 job (32g x 96 rows).
// ---------------------------------------------------------------------------
__global__ __launch_bounds__(64) void ks1(
    const unsigned short* __restrict__ wsu, const float* __restrict__ biasf,
    unsigned short* __restrict__ wsz) {
    __shared__ __align__(16) unsigned short xT[112 * 72];
    __shared__ __align__(16) unsigned short zb[48 * RS_ZB];
    const int b = blockIdx.x, tci = blockIdx.y, t = threadIdx.x;
    const int t0b = tci * 96;
    const unsigned short* xTg = wsz + XTG_U + (b * 1072 + t0b) * 64;
    for (int idx = t; idx < 112 * 8; idx += 64) {
        int r = idx >> 3, q = idx & 7;
        *(uint4v*)&xT[r * 72 + 8 * q] = *(const uint4v*)&xTg[r * 64 + 8 * q];
    }
    __syncthreads();
    conv_core<64, 72, 2, 6, 3, 2, 8, 11, 32, 330, 32, 25, 32, false, 1>(
        xT, wsu + UW1, biasf + BB1, wsz + Z1G_U + b * 330 * 32, nullptr, zb,
        t, tci, tci + 1, t0b);
}

// ---------------------------------------------------------------------------
// ks2: stage2. grid (128, 8), 64 threads = 1 wave = 1 job (gbi = y>>2, tci = y&3).
// ---------------------------------------------------------------------------
__global__ __launch_bounds__(64) void ks2(
    const unsigned short* __restrict__ wsu, const float* __restrict__ biasf,
    unsigned short* __restrict__ wsz) {
    __shared__ __align__(16) unsigned short xT[112 * 40];
    __shared__ __align__(16) unsigned short zb[48 * RS_ZB];
    const int b = blockIdx.x, job = blockIdx.y, t = threadIdx.x;
    const int t0b = (job & 3) * 96;
    const unsigned short* z1g = wsz + Z1G_U + b * 330 * 32;
    for (int idx = t; idx < 112 * 4; idx += 64) {
        int r = idx >> 2, q = idx & 3;
        uint4v v = {0u, 0u, 0u, 0u};
        if (t0b + r < 330) v = *(const uint4v*)&z1g[(t0b + r) * 32 + 8 * q];
        *(uint4v*)&xT[r * 40 + 8 * q] = v;
    }
    __syncthreads();
    conv_core<32, 40, 1, 6, 3, 2, 8, 4, 64, 107, 64, 50, 64, false, 1>(
        xT, wsu + UW2, biasf + BB2, wsz + Z2G_U + b * 107 * 64, nullptr, zb,
        t, job, job + 1, t0b);
}

// ---------------------------------------------------------------------------
// ks34h: stages 3+4 + head, per-sample. 128 blocks x 256 threads.
// ---------------------------------------------------------------------------
__global__ __launch_bounds__(256) void ks34h(
    const unsigned short* __restrict__ wsu, const float* __restrict__ biasf,
    unsigned short* __restrict__ wsz,
    const float* __restrict__ w_cls, const float* __restrict__ b_cls,
    const int* __restrict__ cid,
    const float* __restrict__ hW1, const float* __restrict__ hb1,
    const float* __restrict__ hW2, const float* __restrict__ hb2,
    const float* __restrict__ hg, const float* __restrict__ hbe,
    const float* __restrict__ hm, const float* __restrict__ hv,
    float* __restrict__ out) {
    __shared__ __align__(16) unsigned char smem[49600];
    unsigned short* z2t = (unsigned short*)(smem);            // [112][72] 16128 B
    unsigned short* z3t = (unsigned short*)(smem + 16128);    // [44][136] 11968 B
    float*          z4f = (float*)(smem + 28096);             // [7][200]  5600 B
    unsigned short* zb  = (unsigned short*)(smem + 33696);    // 4*48*36*2 13824 B
    float*          feats = (float*)(smem + 47520);
    float*          h1s   = (float*)(smem + 47536);

    const int b = blockIdx.x, t = threadIdx.x;
    const unsigned short* z2g = wsz + Z2G_U + b * 107 * 64;
    for (int idx = t; idx < 112 * 8; idx += 256) {
        int r = idx >> 3, q = idx & 7;
        uint4v v = {0u, 0u, 0u, 0u};
        if (r < 107) v = *(const uint4v*)&z2g[r * 64 + 8 * q];
        *(uint4v*)&z2t[r * 72 + 8 * q] = v;
    }
    for (int i = t; i < 816; i += 256)      // zero z3t rows 32..43
        *(unsigned int*)&z3t[32 * 136 + 2 * i] = 0u;
    __syncthreads();

    conv_core<64, 72, 2, 6, 3, 2, 8, 1, 128, 32, 128, 100, 136, false, 4>(
        z2t, wsu + UW3, biasf + BB3, z3t, nullptr, zb, t, 0, 4, 0);
    __syncthreads();

    conv_core<128, 136, 4, 2, 2, 1, 4, 1, 224, 7, 200, 200, 200, true, 4>(
        z3t, wsu + UW4, biasf + BB4, nullptr, z4f, zb, t, 0, 7, 0);
    __syncthreads();

    const int wv = t >> 6, lane = t & 63;
    {
        float p = 0.f;
        for (int i = lane; i < 1400; i += 64) {
            int po = i / 200, g = i - po * 200;
            p = fmaf(z4f[i], w_cls[wv * 1400 + g * 7 + po], p);
        }
        p = warp_sum(p);
        if (lane == 0) feats[wv] = p + b_cls[wv];
    }
    __syncthreads();

    const int c = cid[b];
    const float f0 = feats[0], f1 = feats[1], f2 = feats[2], f3 = feats[3];
    for (int h = t; h < 512; h += 256) {
        const float* w1 = &hW1[(c * 512 + h) * 4];
        float v = f0 * w1[0] + f1 * w1[1] + f2 * w1[2] + f3 * w1[3] + hb1[c * 512 + h];
        float sc = hg[c * 512 + h] * rsqrtf(hv[c * 512 + h] + EPS_BN);
        v = (v - hm[c * 512 + h]) * sc + hbe[c * 512 + h];
        h1s[h] = fmaxf(v, 0.f);
    }
    __syncthreads();
    {
        float p = 0.f;
        for (int i = lane; i < 512; i += 64)
            p = fmaf(h1s[i], hW2[(c * 4 + wv) * 512 + i], p);
        p = warp_sum(p);
        if (lane == 0) out[b * 4 + wv] = p + hb2[c * 4 + wv];
    }
}

// ---------------------------------------------------------------------------
extern "C" void kernel_launch(void* const* d_in, const int* in_sizes, int n_in,
                              void* d_out, int out_size, void* d_ws, size_t ws_size,
                              hipStream_t stream) {
    const float* x      = (const float*)d_in[0];
    const int*   cid    = (const int*)d_in[1];
    const float* w_time = (const float*)d_in[2];
    const float* b_time = (const float*)d_in[3];
    const float* w_spat = (const float*)d_in[4];
    const float* w2     = (const float*)d_in[5];
    const float* w3     = (const float*)d_in[6];
    const float* w4     = (const float*)d_in[7];
    const float* w_cls  = (const float*)d_in[8];
    const float* b_cls  = (const float*)d_in[9];
    const float* hW1    = (const float*)d_in[10];
    const float* hb1    = (const float*)d_in[11];
    const float* hW2    = (const float*)d_in[12];
    const float* hb2    = (const float*)d_in[13];
    const float* hg     = (const float*)d_in[14];
    const float* hbe    = (const float*)d_in[15];
    const float* hm     = (const float*)d_in[16];
    const float* hv     = (const float*)d_in[17];
    const float* g1  = (const float*)d_in[18];
    const float* be1 = (const float*)d_in[19];
    const float* m1  = (const float*)d_in[20];
    const float* v1  = (const float*)d_in[21];
    const float* g2  = (const float*)d_in[22];
    const float* be2 = (const float*)d_in[23];
    const float* m2  = (const float*)d_in[24];
    const float* v2  = (const float*)d_in[25];
    const float* g3  = (const float*)d_in[26];
    const float* be3 = (const float*)d_in[27];
    const float* m3  = (const float*)d_in[28];
    const float* v3  = (const float*)d_in[29];
    const float* g4  = (const float*)d_in[30];
    const float* be4 = (const float*)d_in[31];
    const float* m4  = (const float*)d_in[32];
    const float* v4  = (const float*)d_in[33];

    unsigned short* wsz = (unsigned short*)d_ws;
    float* biasf = (float*)((char*)d_ws + 819200);
    float* out = (float*)d_out;

    kprep_tr<<<NPREP + 128 * 17, 256, 0, stream>>>(
        x, w_time, b_time, w_spat, w2, w3, w4,
        g1, be1, m1, v1, g2, be2, m2, v2, g3, be3, m3, v3, g4, be4, m4, v4,
        wsz, biasf);

    ks1<<<dim3(128, 11), 64, 0, stream>>>(wsz, biasf, wsz);
    ks2<<<dim3(128, 8), 64, 0, stream>>>(wsz, biasf, wsz);
    ks34h<<<128, 256, 0, stream>>>(wsz, biasf, wsz, w_cls, b_cls, cid,
                                   hW1, hb1, hW2, hb2, hg, hbe, hm, hv, out);
}